// Round 4
// baseline (189.191 us; speedup 1.0000x reference)
//
#include <hip/hip_runtime.h>
#include <math.h>

// B=2048, S=8, D=1280, K=1 rank-1 common-mode removal.
// R10 (resubmit; R3 bench was a broker acquisition timeout, no data).
// R9 PMC: 78us @ 26% HBM, VALU 14%, Occ 18.6% -- pure latency bound
// (~2-3KB in flight/CU vs ~9KB needed; predicted 2TB/s, measured 2.06).
// Fix: 1 batch/block (2048 blocks), stage the 40KB tile to LDS via
// global_load_lds width=16 (VGPR-free deep queue, ~10KB in flight/wave),
// gram + apply both read LDS (feat read ONCE from HBM), rows padded to
// 5136B -> uniform 8 lanes/slot on every ds_read_b128 (= b128 minimum,
// conflict-free). MFMA 16x16 tile packs 8 rows x 2 k-streams; 8 partial
// gram slots summed in eigen (linear, commutes).
// G = HH + HL + HL^T where f = hi + lo; lo*lo^T ~ 2^-18 rel, dropped.
//  Phase A: stage -> LDS; 4 waves x 2 streams x 5 chunks MFMA gram -> LDS.
//  Phase B: wave0 pre-reduces 8 slots; lane0 serial eigen (proven math).
//  Phase C: apply from LDS tile, stream out. One HBM read + one write.

#define SV 8
#define DV 1280
#define D4 320             // float4 per row
#define BSTRIDE (SV*DV)    // 10240 floats per batch
#define LROW 1284          // padded LDS row: 5136B -> bank slot = row&7
#define GSZ 136            // per-slot: HH[64] + HL[64] + S[8]
#define NSLOT 8            // 4 waves x 2 k-streams

typedef __attribute__((ext_vector_type(8))) short bf16x8;
typedef __attribute__((ext_vector_type(4))) float f32x4;

union BF8 { bf16x8 v; short s[8]; unsigned u[4]; };

__device__ __forceinline__ void stage16(const float* g, float* l) {
    __builtin_amdgcn_global_load_lds(
        (const __attribute__((address_space(1))) unsigned*)g,
        (__attribute__((address_space(3))) unsigned*)l, 16, 0, 0);
}

__global__ __launch_bounds__(256, 2)
void cmr_fused(const float* __restrict__ feat,
               const float* __restrict__ kp,
               const float* __restrict__ cmr_gate,
               float* __restrict__ out, int Bn)
{
    __shared__ float fl[SV * LROW];        // 41088B padded feat tile
    __shared__ float lg[NSLOT][GSZ];       // 4352B gram partials
    __shared__ float lc[17];               // a[8], coef[8], bconst

    const int tid  = threadIdx.x;
    const int lane = tid & 63;
    const int h    = tid >> 6;             // wave id
    const int b    = blockIdx.x;           // 1 batch per block

    // ---------------- Phase A0: stage 40KB tile to LDS ----------------
    {
        const float* __restrict__ gb = feat + (size_t)b * BSTRIDE;
#pragma unroll
        for (int i = 0; i < 10; ++i) {
            const int chunk = h * 10 + i;          // 0..39, 1KB each
            const int r  = chunk / 5;
            const int cc = chunk % 5;
            stage16(gb + (size_t)r * DV + cc * 256 + lane * 4,
                    &fl[r * LROW + cc * 256]);
        }
    }
    __syncthreads();   // drains vmcnt before barrier (compiler-inserted)

    // ---------------- Phase A1: MFMA gram partials -> LDS ----------------
    {
        const int m      = lane & 15;      // 0-7: k-stream 0, 8-15: k-stream 1
        const int quad   = lane >> 4;      // k sub-offset = quad*8
        const int row    = m & 7;
        const int stream = h * 2 + (m >> 3);   // 0..7

        const float* __restrict__ fr = &fl[row * LROW];

        BF8 ones;
#pragma unroll
        for (int j = 0; j < 4; ++j) ones.u[j] = 0x3F803F80u;   // bf16 1.0 pairs

        f32x4 accHH = {0.f, 0.f, 0.f, 0.f};
        f32x4 accHL = {0.f, 0.f, 0.f, 0.f};
        f32x4 accS  = {0.f, 0.f, 0.f, 0.f};

#pragma unroll
        for (int c = 0; c < 5; ++c) {
            const int k0 = (stream * 5 + c) * 32 + quad * 8;
            const float4 x0 = *(const float4*)(fr + k0);
            const float4 x1 = *(const float4*)(fr + k0 + 4);
            float x[8] = {x0.x, x0.y, x0.z, x0.w, x1.x, x1.y, x1.z, x1.w};
            BF8 hi, lo;
#pragma unroll
            for (int j = 0; j < 4; ++j) {
                unsigned hp, lp;
                asm("v_cvt_pk_bf16_f32 %0, %1, %2"
                    : "=v"(hp) : "v"(x[2*j]), "v"(x[2*j+1]));
                const float h0 = __uint_as_float(hp << 16);
                const float h1 = __uint_as_float(hp & 0xFFFF0000u);
                const float l0 = x[2*j]     - h0;
                const float l1 = x[2*j + 1] - h1;
                asm("v_cvt_pk_bf16_f32 %0, %1, %2"
                    : "=v"(lp) : "v"(l0), "v"(l1));
                hi.u[j] = hp;
                lo.u[j] = lp;
            }
            accHH = __builtin_amdgcn_mfma_f32_16x16x32_bf16(hi.v, hi.v,   accHH, 0, 0, 0);
            accHL = __builtin_amdgcn_mfma_f32_16x16x32_bf16(hi.v, lo.v,   accHL, 0, 0, 0);
            accS  = __builtin_amdgcn_mfma_f32_16x16x32_bf16(hi.v, ones.v, accS,  0, 0, 0);
            accS  = __builtin_amdgcn_mfma_f32_16x16x32_bf16(lo.v, ones.v, accS,  0, 0, 0);
        }

        // C/D layout: lane l, reg r -> row=(l>>4)*4+r, col=l&15  [m89/m91]
        // Diagonal 8x8 blocks = per-stream grams; off-diagonal = cross-stream junk.
        const int colh = (lane & 15) >> 3;         // which k-stream's columns
        const int col  = lane & 7;
#pragma unroll
        for (int r = 0; r < 4; ++r) {
            const int rowg = quad * 4 + r;         // 0..15
            if ((rowg >> 3) == colh) {             // same-stream diagonal block
                float* gs = &lg[h * 2 + colh][0];
                gs[(rowg & 7) * 8 + col]      = accHH[r];
                gs[64 + (rowg & 7) * 8 + col] = accHL[r];
            }
        }
        if ((lane & 15) == 0) {                    // col-0 lanes: 0,16,32,48
#pragma unroll
            for (int r = 0; r < 4; ++r) {
                const int rowg = quad * 4 + r;
                lg[h * 2 + (rowg >> 3)][128 + (rowg & 7)] = accS[r];
            }
        }
    }
    __syncthreads();

    // ---------------- Phase B: eigen ----------------
    if (h == 0) {
        // wave-parallel pre-reduce of the 8 slots into slot 0
        for (int idx = lane; idx < GSZ; idx += 64) {
            float s = lg[0][idx];
#pragma unroll
            for (int hh = 1; hh < NSLOT; ++hh) s += lg[hh][idx];
            lg[0][idx] = s;
        }
        asm volatile("s_waitcnt lgkmcnt(0)" ::: "memory");

        if (lane == 0) {
            const float* __restrict__ gh = &lg[0][0];
            float G[8][8], S[8], mu[8], sig[8], rsig[8];
#pragma unroll
            for (int i = 0; i < 8; ++i) {
#pragma unroll
                for (int j = 0; j < 8; ++j)
                    G[i][j] = gh[i * 8 + j] + gh[64 + i * 8 + j] + gh[64 + j * 8 + i];
                S[i] = gh[128 + i];
            }
            const float invD = 1.f / (float)DV;
#pragma unroll
            for (int i = 0; i < 8; ++i) {
                mu[i] = S[i] * invD;
                const float var = fmaxf(G[i][i] * invD - mu[i] * mu[i], 0.f);
                sig[i]  = sqrtf(var) + 1e-8f;          // numpy std(ddof=0)+1e-8
                rsig[i] = 1.f / sig[i];
            }
#pragma unroll
            for (int i = 0; i < 8; ++i)
#pragma unroll
                for (int j = 0; j < 8; ++j)
                    G[i][j] = (G[i][j] - (float)DV * mu[i] * mu[j]) * rsig[i] * rsig[j];

            float tr = 0.f;
#pragma unroll
            for (int i = 0; i < 8; ++i) tr += G[i][i];

            // ---- 12x symmetric trace-normalized squaring ----
            float A[8][8];
            {
                const float rt = 1.f / fmaxf(tr, 1e-30f);
#pragma unroll
                for (int i = 0; i < 8; ++i)
#pragma unroll
                    for (int j = 0; j < 8; ++j) A[i][j] = G[i][j] * rt;
            }
#pragma unroll
            for (int t = 0; t < 12; ++t) {
                float Bm[8][8];
                float trB = 0.f;
#pragma unroll
                for (int i = 0; i < 8; ++i)
#pragma unroll
                    for (int j = i; j < 8; ++j) {
                        float acc = 0.f;
#pragma unroll
                        for (int k = 0; k < 8; ++k)
                            acc = fmaf(A[i][k], A[j][k], acc);   // A symmetric
                        Bm[i][j] = acc;
                        if (i == j) trB += acc;
                    }
                const float rt = 1.f / fmaxf(trB, 1e-30f);
#pragma unroll
                for (int i = 0; i < 8; ++i)
#pragma unroll
                    for (int j = i; j < 8; ++j) {
                        const float v = Bm[i][j] * rt;
                        A[i][j] = v; A[j][i] = v;
                    }
            }
            // diag argmax -> dominant column ~ u1 (A ~= u u^T)
            int bj = 0; float best = A[0][0];
#pragma unroll
            for (int k = 1; k < 8; ++k)
                if (A[k][k] > best) { best = A[k][k]; bj = k; }
            float u[8];
#pragma unroll
            for (int i = 0; i < 8; ++i) {
                float v = A[i][0];
#pragma unroll
                for (int k = 1; k < 8; ++k) v = (bj == k) ? A[i][k] : v;
                u[i] = v;
            }
            {
                float nn = 0.f;
#pragma unroll
                for (int i = 0; i < 8; ++i) nn = fmaf(u[i], u[i], nn);
                const float r = rsqrtf(fmaxf(nn, 1e-30f));
#pragma unroll
                for (int i = 0; i < 8; ++i) u[i] *= r;
            }
            // 2 power-iteration polish steps on G
#pragma unroll
            for (int it = 0; it < 2; ++it) {
                float y[8]; float ny = 0.f;
#pragma unroll
                for (int i = 0; i < 8; ++i) {
                    float acc = 0.f;
#pragma unroll
                    for (int k = 0; k < 8; ++k) acc = fmaf(G[i][k], u[k], acc);
                    y[i] = acc; ny = fmaf(acc, acc, ny);
                }
                const float r = rsqrtf(fmaxf(ny, 1e-30f));
#pragma unroll
                for (int i = 0; i < 8; ++i) u[i] = y[i] * r;
            }
            // Rayleigh quotient
            float lam = 0.f;
#pragma unroll
            for (int i = 0; i < 8; ++i) {
                float acc = 0.f;
#pragma unroll
                for (int k = 0; k < 8; ++k) acc = fmaf(G[i][k], u[k], acc);
                lam = fmaf(u[i], acc, lam);
            }
            const float pc1 = lam / (tr + 1e-8f);

            const float gate = 1.f / (1.f + expf(-cmr_gate[0]));
            const float kpg  = (kp[b] >= 5.0f) ? 1.5f : 1.0f;
            const float Gt   = gate * kpg;

            float bc = 0.f;
#pragma unroll
            for (int i = 0; i < 8; ++i) bc = fmaf(u[i] * rsig[i], mu[i], bc);

#pragma unroll
            for (int i = 0; i < 8; ++i) {
                lc[i]     = u[i] * rsig[i];     // a_i   : p = sum a_s f[s,d] - bc
                lc[8 + i] = Gt * sig[i] * u[i]; // coef_i: out = f - coef_s * p
            }
            lc[16] = bc;
            out[(size_t)Bn * BSTRIDE + b] = pc1;
            out[(size_t)Bn * BSTRIDE + Bn + b] =
                (pc1 >= 0.6f ? 1.f : 0.f) + (pc1 >= 0.8f ? 1.f : 0.f);
        }
    }
    __syncthreads();

    // ---------------- Phase C: apply from LDS tile, stream out ----------------
    {
        float a[8], c[8];
#pragma unroll
        for (int s = 0; s < 8; ++s) { a[s] = lc[s]; c[s] = lc[8 + s]; }
        const float bc = lc[16];

        float4* __restrict__ o4 = (float4*)(out + (size_t)b * BSTRIDE);

        for (int col = tid; col < D4; col += 256) {
            float4 f[8];
#pragma unroll
            for (int s = 0; s < 8; ++s)
                f[s] = *(const float4*)&fl[s * LROW + col * 4];

            float4 p = make_float4(-bc, -bc, -bc, -bc);
#pragma unroll
            for (int s = 0; s < 8; ++s) {
                p.x = fmaf(a[s], f[s].x, p.x);
                p.y = fmaf(a[s], f[s].y, p.y);
                p.z = fmaf(a[s], f[s].z, p.z);
                p.w = fmaf(a[s], f[s].w, p.w);
            }
#pragma unroll
            for (int s = 0; s < 8; ++s) {
                float4 o;
                o.x = fmaf(-c[s], p.x, f[s].x);
                o.y = fmaf(-c[s], p.y, f[s].y);
                o.z = fmaf(-c[s], p.z, f[s].z);
                o.w = fmaf(-c[s], p.w, f[s].w);
                o4[s * D4 + col] = o;
            }
        }
    }
}

extern "C" void kernel_launch(void* const* d_in, const int* in_sizes, int n_in,
                              void* d_out, int out_size, void* d_ws, size_t ws_size,
                              hipStream_t stream) {
    const float* feat = (const float*)d_in[0];
    const float* kp   = (const float*)d_in[1];
    const float* gate = (const float*)d_in[2];
    float* out = (float*)d_out;
    const int Bn = in_sizes[0] / BSTRIDE;        // 2048
    (void)d_ws; (void)ws_size;

    cmr_fused<<<Bn, 256, 0, stream>>>(feat, kp, gate, out, Bn);
}

// Round 10
// 171.556 us; speedup vs baseline: 1.1028x; 1.1028x over previous
//
#include <hip/hip_runtime.h>
#include <math.h>

// B=2048, S=8, D=1280, K=1 rank-1 common-mode removal.
// R11 (5th resubmit; R5-R9 benches were broker acquisition timeouts).
// ONE WAVE = ONE BATCH, everything in registers, ZERO barriers/LDS/MFMA.
// History: R7/R8 split ~76us, R9 fused 78us, R10 gload_lds 88us -- all
// plateau ~2 TB/s because barrier-aligned phases serialize (CU alternates
// HBM-busy/VALU-idle). Fix: 64-thread blocks, each wave loads its 40KB
// batch as 40 independent float4 loads (40KB/wave in flight -> BW-bound),
// computes fp32 gram partials per-lane (no bf16 split, better accuracy),
// butterfly-reduces 44 values (all lanes get G), runs the PROVEN eigen
// chain redundantly on all 64 lanes (no divergence, no broadcast), applies
// from registers, streams out. Wave-granular retire overlaps generations.
// VGPR control: upper-triangle G/A/Bm via constant-index accessors,
// peak ~330 regs < 450 no-spill line; __launch_bounds__(64,1) allows it.

#define SV 8
#define DV 1280
#define D4 320             // float4 per row
#define BSTRIDE (SV*DV)    // 10240 floats per batch

__device__ __forceinline__ float wsum(float v) {
    v += __shfl_xor(v, 32);
    v += __shfl_xor(v, 16);
    v += __shfl_xor(v, 8);
    v += __shfl_xor(v, 4);
    v += __shfl_xor(v, 2);
    v += __shfl_xor(v, 1);
    return v;
}

// constant-index upper-triangle accessors (i,k compile-time constants)
#define GU(i,k) ((i) <= (k) ? G[i][k] : G[k][i])
#define AU(i,k) ((i) <= (k) ? A[i][k] : A[k][i])

__global__ __launch_bounds__(64, 1)
void cmr_wave(const float* __restrict__ feat,
              const float* __restrict__ kp,
              const float* __restrict__ cmr_gate,
              float* __restrict__ out, int Bn)
{
    const int lane = threadIdx.x;          // 0..63
    const int b    = blockIdx.x;           // 1 batch per wave

    const float4* __restrict__ f4 =
        (const float4*)(feat + (size_t)b * BSTRIDE);

    // ---- load whole batch: 40 independent coalesced float4 loads ----
    float4 f[8][5];
#pragma unroll
    for (int s = 0; s < 8; ++s)
#pragma unroll
        for (int c = 0; c < 5; ++c)
            f[s][c] = f4[s * D4 + c * 64 + lane];

    // ---- per-lane gram partials (upper triangle) + row sums ----
    float G[8][8];                          // only j>=i written (DCE'd lower)
    float S[8];
#pragma unroll
    for (int i = 0; i < 8; ++i) {
        S[i] = 0.f;
#pragma unroll
        for (int j = i; j < 8; ++j) G[i][j] = 0.f;
    }
#pragma unroll
    for (int c = 0; c < 5; ++c) {
#pragma unroll
        for (int i = 0; i < 8; ++i) {
            const float4 a = f[i][c];
            S[i] += (a.x + a.y) + (a.z + a.w);
#pragma unroll
            for (int j = i; j < 8; ++j) {
                const float4 q = f[j][c];
                G[i][j] = fmaf(a.x, q.x,
                          fmaf(a.y, q.y,
                          fmaf(a.z, q.z,
                          fmaf(a.w, q.w, G[i][j]))));
            }
        }
    }
    // ---- butterfly reduce: every lane ends with the full sums ----
#pragma unroll
    for (int i = 0; i < 8; ++i) {
        S[i] = wsum(S[i]);
#pragma unroll
        for (int j = i; j < 8; ++j) G[i][j] = wsum(G[i][j]);
    }

    // ---- eigen (proven math; all 64 lanes redundantly, zero divergence) ----
    float mu[8], sig[8], rsig[8];
    const float invD = 1.f / (float)DV;
#pragma unroll
    for (int i = 0; i < 8; ++i) {
        mu[i] = S[i] * invD;
        const float var = fmaxf(G[i][i] * invD - mu[i] * mu[i], 0.f);
        sig[i]  = sqrtf(var) + 1e-8f;       // numpy std(ddof=0)+1e-8
        rsig[i] = 1.f / sig[i];
    }
    // normalize: G <- Gram of standardized rows (upper triangle)
#pragma unroll
    for (int i = 0; i < 8; ++i)
#pragma unroll
        for (int j = i; j < 8; ++j)
            G[i][j] = (G[i][j] - (float)DV * mu[i] * mu[j]) * rsig[i] * rsig[j];

    float tr = 0.f;
#pragma unroll
    for (int i = 0; i < 8; ++i) tr += G[i][i];

    // ---- 12x symmetric trace-normalized squaring (upper triangle) ----
    float A[8][8];                          // only j>=i written
    {
        const float rt = 1.f / fmaxf(tr, 1e-30f);
#pragma unroll
        for (int i = 0; i < 8; ++i)
#pragma unroll
            for (int j = i; j < 8; ++j) A[i][j] = G[i][j] * rt;
    }
#pragma unroll
    for (int t = 0; t < 12; ++t) {
        float Bm[8][8];                     // only j>=i written
        float trB = 0.f;
#pragma unroll
        for (int i = 0; i < 8; ++i)
#pragma unroll
            for (int j = i; j < 8; ++j) {
                float acc = 0.f;
#pragma unroll
                for (int k = 0; k < 8; ++k)
                    acc = fmaf(AU(i, k), AU(j, k), acc);   // A symmetric
                Bm[i][j] = acc;
                if (i == j) trB += acc;
            }
        const float rt = 1.f / fmaxf(trB, 1e-30f);
#pragma unroll
        for (int i = 0; i < 8; ++i)
#pragma unroll
            for (int j = i; j < 8; ++j) A[i][j] = Bm[i][j] * rt;
    }
    // diag argmax -> dominant column ~ u1 (A ~= u u^T)
    int bj = 0; float best = A[0][0];
#pragma unroll
    for (int k = 1; k < 8; ++k)
        if (A[k][k] > best) { best = A[k][k]; bj = k; }
    float u[8];
#pragma unroll
    for (int i = 0; i < 8; ++i) {
        float v = AU(i, 0);
#pragma unroll
        for (int k = 1; k < 8; ++k) v = (bj == k) ? AU(i, k) : v;
        u[i] = v;
    }
    {
        float nn = 0.f;
#pragma unroll
        for (int i = 0; i < 8; ++i) nn = fmaf(u[i], u[i], nn);
        const float r = rsqrtf(fmaxf(nn, 1e-30f));
#pragma unroll
        for (int i = 0; i < 8; ++i) u[i] *= r;
    }
    // 2 power-iteration polish steps on G
#pragma unroll
    for (int it = 0; it < 2; ++it) {
        float y[8]; float ny = 0.f;
#pragma unroll
        for (int i = 0; i < 8; ++i) {
            float acc = 0.f;
#pragma unroll
            for (int k = 0; k < 8; ++k) acc = fmaf(GU(i, k), u[k], acc);
            y[i] = acc; ny = fmaf(acc, acc, ny);
        }
        const float r = rsqrtf(fmaxf(ny, 1e-30f));
#pragma unroll
        for (int i = 0; i < 8; ++i) u[i] = y[i] * r;
    }
    // Rayleigh quotient
    float lam = 0.f;
#pragma unroll
    for (int i = 0; i < 8; ++i) {
        float acc = 0.f;
#pragma unroll
        for (int k = 0; k < 8; ++k) acc = fmaf(GU(i, k), u[k], acc);
        lam = fmaf(u[i], acc, lam);
    }
    const float pc1 = lam / (tr + 1e-8f);

    const float gate = 1.f / (1.f + expf(-cmr_gate[0]));
    const float kpg  = (kp[b] >= 5.0f) ? 1.5f : 1.0f;
    const float Gt   = gate * kpg;

    float av[8], cv[8];
#pragma unroll
    for (int i = 0; i < 8; ++i) {
        av[i] = u[i] * rsig[i];             // p = sum a_s f[s,d] - bc
        cv[i] = Gt * sig[i] * u[i];         // out = f - c_s * p
    }
    float bc = 0.f;
#pragma unroll
    for (int i = 0; i < 8; ++i) bc = fmaf(av[i], mu[i], bc);

    if (lane == 0) {
        out[(size_t)Bn * BSTRIDE + b] = pc1;
        out[(size_t)Bn * BSTRIDE + Bn + b] =
            (pc1 >= 0.6f ? 1.f : 0.f) + (pc1 >= 0.8f ? 1.f : 0.f);
    }

    // ---- apply from registers, coalesced stream out ----
    float4* __restrict__ o4 = (float4*)(out + (size_t)b * BSTRIDE);
#pragma unroll
    for (int c = 0; c < 5; ++c) {
        float4 p = make_float4(-bc, -bc, -bc, -bc);
#pragma unroll
        for (int s = 0; s < 8; ++s) {
            p.x = fmaf(av[s], f[s][c].x, p.x);
            p.y = fmaf(av[s], f[s][c].y, p.y);
            p.z = fmaf(av[s], f[s][c].z, p.z);
            p.w = fmaf(av[s], f[s][c].w, p.w);
        }
#pragma unroll
        for (int s = 0; s < 8; ++s) {
            float4 o;
            o.x = fmaf(-cv[s], p.x, f[s][c].x);
            o.y = fmaf(-cv[s], p.y, f[s][c].y);
            o.z = fmaf(-cv[s], p.z, f[s][c].z);
            o.w = fmaf(-cv[s], p.w, f[s][c].w);
            o4[s * D4 + c * 64 + lane] = o;
        }
    }
}

extern "C" void kernel_launch(void* const* d_in, const int* in_sizes, int n_in,
                              void* d_out, int out_size, void* d_ws, size_t ws_size,
                              hipStream_t stream) {
    const float* feat = (const float*)d_in[0];
    const float* kp   = (const float*)d_in[1];
    const float* gate = (const float*)d_in[2];
    float* out = (float*)d_out;
    const int Bn = in_sizes[0] / BSTRIDE;        // 2048
    (void)d_ws; (void)ws_size;

    cmr_wave<<<Bn, 64, 0, stream>>>(feat, kp, gate, out, Bn);
}